// Round 4
// baseline (747.793 us; speedup 1.0000x reference)
//
#include <hip/hip_runtime.h>
#include <math.h>

#define T_STEPS 256
#define BATCH   4096
#define HID     64
#define MW      128
#define DOUT    8
#define RPB     16    // rows per block -> grid = 256 = 1 block/CU (grid-limited)
#define NTH     512   // 8 waves: phase1/2: (mlp 2) x (neuron-quarter 4)
#define AS      72    // Ain/zb row stride in halfs (144B)
#define HS      136   // h1/h2 row stride in halfs (272B)

typedef _Float16 half8 __attribute__((ext_vector_type(8)));
typedef _Float16 half4 __attribute__((ext_vector_type(4)));
typedef float    f32x4 __attribute__((ext_vector_type(4)));

__device__ __forceinline__ float fast_rcp(float x) { return __builtin_amdgcn_rcpf(x); }
// silu WITHOUT the 0.909 (folded into next layer's f16 weights)
__device__ __forceinline__ float silu(float x) {
    float e = __expf(-x);
    return x * fast_rcp(1.0f + e);
}
__device__ __forceinline__ float fast_tanh(float x) {
    float e = __expf(2.0f * x);
    return 1.0f - 2.0f * fast_rcp(e + 1.0f);
}

#define MFMA(a, b, c) __builtin_amdgcn_mfma_f32_16x16x32_f16((a), (b), (c), 0, 0, 0)

// Transposed-role MFMA org (weights = A, activations = B, batch = N):
//   A[m][k]: m = lane&15 (out-neuron in tile), k = (lane>>4)*8 + j
//   B[k][n]: n = lane&15 (batch row),          k = (lane>>4)*8 + j
//   C/D   : col n = lane&15 (batch), row m = (lane>>4)*4 + reg (out-neuron)
// => each lane's 4 C-values are 4 CONSECUTIVE out-neurons of ONE batch row:
//    all activation/state stores become packed b64, bias init is a b128 read.

__global__ __launch_bounds__(NTH, 1)   // grid = 1 block/CU: VGPRs free
void sde_kernel(const float* __restrict__ ts,
                const float* __restrict__ dW,
                const float* __restrict__ dW0, const float* __restrict__ db0,
                const float* __restrict__ dW1, const float* __restrict__ db1,
                const float* __restrict__ dWo, const float* __restrict__ dbo,
                const float* __restrict__ gW0, const float* __restrict__ gb0,
                const float* __restrict__ gW1, const float* __restrict__ gb1,
                const float* __restrict__ gWo, const float* __restrict__ gbo,
                const float* __restrict__ rW,  const float* __restrict__ rb,
                float* __restrict__ out)
{
    __shared__ __align__(16) _Float16 Ain_hi[RPB][AS];  // [batch][dim], hi part
    __shared__ __align__(16) _Float16 Ain_lo[RPB][AS];  // lo part (fp32-exact split)
    __shared__ __align__(16) _Float16 h1b[2][RPB][HS];  // [mlp][batch][neuron]
    __shared__ __align__(16) _Float16 h2b[2][RPB][HS];
    __shared__ __align__(16) _Float16 zb[2][RPB][AS];   // z stash [batch][dim]
    __shared__ __align__(16) float    bias1t[2 * MW];   // L1 bias incl. t*W0row0
    __shared__ float tsS[T_STEPS];

    const int tid  = threadIdx.x;
    const int lane = tid & 63;
    const int wid  = tid >> 6;     // 0..7
    const int l15  = lane & 15;    // batch row (N) everywhere
    const int quad = lane >> 4;
    const int mlp  = wid >> 2;     // phase-1/2 role: 0 = drift, 1 = diff
    const int nq   = wid & 3;      // out-neuron quarter (32-col slice of L1/L2)
    const int rowbase = blockIdx.x * RPB;

    for (int i = tid; i < T_STEPS; i += NTH) tsS[i] = ts[i];

    const float t0   = ts[0];
    const float dt   = ts[1] - t0;
    const float sqdt = sqrtf(dt);

    // ---------------- static weight fragments (A-operand) ----------------
    const float* W0 = mlp ? gW0 : dW0;   // (65,128); row 0 = t weights
    const float* W1 = mlp ? gW1 : dW1;   // (128,128)

    half8 bw1[2][2], bw2[4][2];
    #pragma unroll
    for (int kt = 0; kt < 2; ++kt)
        #pragma unroll
        for (int nt = 0; nt < 2; ++nt) {
            half8 v;
            #pragma unroll
            for (int j = 0; j < 8; ++j) {
                const int k = kt * 32 + quad * 8 + j;
                const int m = nq * 32 + nt * 16 + l15;
                v[j] = (_Float16)W0[(1 + k) * MW + m];
            }
            bw1[kt][nt] = v;
        }
    #pragma unroll
    for (int kt = 0; kt < 4; ++kt)
        #pragma unroll
        for (int nt = 0; nt < 2; ++nt) {
            half8 v;
            #pragma unroll
            for (int j = 0; j < 8; ++j) {
                const int k = kt * 32 + quad * 8 + j;
                const int m = nq * 32 + nt * 16 + l15;
                v[j] = (_Float16)(0.909f * W1[k * MW + m]);   // 0.909 folded
            }
            bw2[kt][nt] = v;
        }

    f32x4 b2v4[2];
    {
        const float* b1p = mlp ? gb1 : db1;
        #pragma unroll
        for (int nt = 0; nt < 2; ++nt)
            b2v4[nt] = *(const f32x4*)&b1p[nq * 32 + nt * 16 + quad * 4];
    }

    // ---------------- phase-3 state (waves 0-3) ----------------
    // state wave w owns batch l15, dims w*16 + quad*4 + {0..3}
    const int dbase = (wid & 3) * 16 + quad * 4;

    half8 bw3f[4], bw3g[4];
    f32x4 b3f4 = {0,0,0,0}, b3g4 = {0,0,0,0};
    float z[4], zh[4], fold[4], gold[4], dwr[4], dn[4];
    if (wid < 4) {
        #pragma unroll
        for (int kt = 0; kt < 4; ++kt) {
            half8 vf, vg;
            #pragma unroll
            for (int j = 0; j < 8; ++j) {
                const int k = kt * 32 + quad * 8 + j;
                const int m = wid * 16 + l15;      // out-dim within Wo
                vf[j] = (_Float16)(0.909f * dWo[k * HID + m]);
                vg[j] = (_Float16)(0.909f * gWo[k * HID + m]);
            }
            bw3f[kt] = vf;
            bw3g[kt] = vg;
        }
        b3f4 = *(const f32x4*)&dbo[dbase];
        b3g4 = *(const f32x4*)&gbo[dbase];
        f32x4 d0 = *(const f32x4*)&dW[(size_t)(rowbase + l15) * HID + dbase];
        #pragma unroll
        for (int i = 0; i < 4; ++i) {
            z[i] = 1.0f; zh[i] = 1.0f; dwr[i] = 0.0f; dn[i] = d0[i];
        }
        half4 ones, zeros;
        #pragma unroll
        for (int i = 0; i < 4; ++i) { ones[i] = (_Float16)1.0f; zeros[i] = (_Float16)0.0f; }
        *(half4*)&Ain_hi[l15][dbase] = ones;    // x0 = ones
        *(half4*)&Ain_lo[l15][dbase] = zeros;
    }

    // readout fragments (wave 4): A = rW^T (M = 8 out dims, rows 8-15 dead)
    half8 brd[2];
    f32x4 rbv4 = {0,0,0,0};
    if (wid == 4) {
        #pragma unroll
        for (int kt = 0; kt < 2; ++kt) {
            half8 v;
            #pragma unroll
            for (int j = 0; j < 8; ++j) {
                const int k = kt * 32 + quad * 8 + j;
                v[j] = (l15 < 8) ? (_Float16)rW[k * DOUT + l15] : (_Float16)0.0f;
            }
            brd[kt] = v;
        }
        if (quad < 2) rbv4 = *(const f32x4*)&rb[quad * 4];
    }

    // t-folded L1 bias owned by waves 4..7 (256 threads cover 2*MW slots)
    float b0s = 0.0f, w0s = 0.0f;
    if (tid >= 256) {
        const int idx = tid - 256;
        b0s = (idx < MW ? db0 : gb0)[idx & (MW - 1)];
        w0s = (idx < MW ? dW0 : gW0)[idx & (MW - 1)];  // W0 row 0
        bias1t[idx] = b0s + t0 * w0s;
    }
    __syncthreads();

    const int koff = quad * 8;

    for (int n = 1; n <= T_STEPS; ++n) {
        // ================= Phase 1: Layer 1, 64 -> 128 (split-B hi/lo) ========
        {
            half8 bh[2], bl[2];
            #pragma unroll
            for (int kt = 0; kt < 2; ++kt) {
                bh[kt] = *(const half8*)&Ain_hi[l15][kt * 32 + koff];
                bl[kt] = *(const half8*)&Ain_lo[l15][kt * 32 + koff];
            }
            f32x4 acc[2];
            #pragma unroll
            for (int nt = 0; nt < 2; ++nt)
                acc[nt] = *(const f32x4*)&bias1t[mlp * MW + nq * 32 + nt * 16 + quad * 4];
            #pragma unroll
            for (int nt = 0; nt < 2; ++nt)
                #pragma unroll
                for (int kt = 0; kt < 2; ++kt) {
                    acc[nt] = MFMA(bw1[kt][nt], bh[kt], acc[nt]);
                    acc[nt] = MFMA(bw1[kt][nt], bl[kt], acc[nt]);
                }
            #pragma unroll
            for (int nt = 0; nt < 2; ++nt) {
                half4 hv;
                #pragma unroll
                for (int i2 = 0; i2 < 4; ++i2) hv[i2] = (_Float16)silu(acc[nt][i2]);
                *(half4*)&h1b[mlp][l15][nq * 32 + nt * 16 + quad * 4] = hv;
            }
        }
        __syncthreads();

        // ================= Phase 2: Layer 2, 128 -> 128 =================
        {
            half8 b_[4];
            #pragma unroll
            for (int kt = 0; kt < 4; ++kt)
                b_[kt] = *(const half8*)&h1b[mlp][l15][kt * 32 + koff];
            f32x4 acc[2];
            #pragma unroll
            for (int nt = 0; nt < 2; ++nt) acc[nt] = b2v4[nt];
            #pragma unroll
            for (int nt = 0; nt < 2; ++nt)
                #pragma unroll
                for (int kt = 0; kt < 4; ++kt)
                    acc[nt] = MFMA(bw2[kt][nt], b_[kt], acc[nt]);
            #pragma unroll
            for (int nt = 0; nt < 2; ++nt) {
                half4 hv;
                #pragma unroll
                for (int i2 = 0; i2 < 4; ++i2) hv[i2] = (_Float16)silu(acc[nt][i2]);
                *(half4*)&h2b[mlp][l15][nq * 32 + nt * 16 + quad * 4] = hv;
            }
        }
        __syncthreads();

        // ===== Phase 3: L3 f&g (waves 0-3, in-register update);
        //                readout + bias refresh (waves 4-7) =====
        if (wid < 4) {
            half8 b_[4];
            #pragma unroll
            for (int kt = 0; kt < 4; ++kt)
                b_[kt] = *(const half8*)&h2b[0][l15][kt * 32 + koff];
            f32x4 accF = b3f4;
            #pragma unroll
            for (int kt = 0; kt < 4; ++kt)
                accF = MFMA(bw3f[kt], b_[kt], accF);
            #pragma unroll
            for (int kt = 0; kt < 4; ++kt)
                b_[kt] = *(const half8*)&h2b[1][l15][kt * 32 + koff];
            f32x4 accG = b3g4;
            #pragma unroll
            for (int kt = 0; kt < 4; ++kt)
                accG = MFMA(bw3g[kt], b_[kt], accG);

            const int p = n & 1;
            float fn[4], gn[4];
            #pragma unroll
            for (int i = 0; i < 4; ++i) {
                fn[i] = fast_tanh(accF[i]);
                gn[i] = fast_tanh(accG[i]);
            }
            if (n > 1) {
                #pragma unroll
                for (int i = 0; i < 4; ++i)
                    z[i] += 0.5f * (fold[i] + fn[i]) * dt + 0.5f * (gold[i] + gn[i]) * dwr[i];
            }
            half4 zp;
            #pragma unroll
            for (int i = 0; i < 4; ++i) zp[i] = (_Float16)z[i];
            *(half4*)&zb[p][l15][dbase] = zp;

            if (n < T_STEPS) {
                const int np = (n < T_STEPS - 2) ? n : (T_STEPS - 2);
                f32x4 dn4 = *(const f32x4*)&dW[(size_t)np * (BATCH * HID)
                                               + (size_t)(rowbase + l15) * HID + dbase];
                half4 hip, lop;
                #pragma unroll
                for (int i = 0; i < 4; ++i) {
                    dwr[i] = dn[i] * sqdt;
                    dn[i]  = dn4[i];
                    zh[i]  = 2.0f * z[i] - zh[i] + fn[i] * dt + gn[i] * dwr[i];
                    const _Float16 hi = (_Float16)zh[i];
                    hip[i] = hi;
                    lop[i] = (_Float16)(zh[i] - (float)hi);
                }
                *(half4*)&Ain_hi[l15][dbase] = hip;
                *(half4*)&Ain_lo[l15][dbase] = lop;
            }
            #pragma unroll
            for (int i = 0; i < 4; ++i) { fold[i] = fn[i]; gold[i] = gn[i]; }
        } else {
            // readout of z_{n-2} via MFMA (wave 4); zb[(n-1)&1] barrier-separated
            if (wid == 4 && n >= 2) {
                const int q = (n - 1) & 1, s = n - 2;
                half8 z0 = *(const half8*)&zb[q][l15][koff];
                half8 z1 = *(const half8*)&zb[q][l15][32 + koff];
                f32x4 racc = rbv4;
                racc = MFMA(brd[0], z0, racc);
                racc = MFMA(brd[1], z1, racc);
                float* orow = out + (size_t)(rowbase + l15) * (T_STEPS * 9) + (size_t)s * 9;
                if (quad < 2) {
                    #pragma unroll
                    for (int i2 = 0; i2 < 4; ++i2)
                        orow[1 + quad * 4 + i2] = racc[i2];
                } else if (quad == 2) {
                    orow[0] = tsS[s];
                }
            }
            if (n < T_STEPS) bias1t[tid - 256] = b0s + tsS[n] * w0s;
        }
        __syncthreads();
    }

    // ---- epilogue: readout of z_255 (stashed in zb[0] at step 256) ----
    if (wid == 4) {
        const int s = T_STEPS - 1;
        half8 z0 = *(const half8*)&zb[0][l15][koff];
        half8 z1 = *(const half8*)&zb[0][l15][32 + koff];
        f32x4 racc = rbv4;
        racc = MFMA(brd[0], z0, racc);
        racc = MFMA(brd[1], z1, racc);
        float* orow = out + (size_t)(rowbase + l15) * (T_STEPS * 9) + (size_t)s * 9;
        if (quad < 2) {
            #pragma unroll
            for (int i2 = 0; i2 < 4; ++i2)
                orow[1 + quad * 4 + i2] = racc[i2];
        } else if (quad == 2) {
            orow[0] = tsS[s];
        }
    }
}

extern "C" void kernel_launch(void* const* d_in, const int* in_sizes, int n_in,
                              void* d_out, int out_size, void* d_ws, size_t ws_size,
                              hipStream_t stream) {
    const float* ts  = (const float*)d_in[0];
    const float* dW  = (const float*)d_in[2];
    const float* dW0 = (const float*)d_in[3];
    const float* db0 = (const float*)d_in[4];
    const float* dW1 = (const float*)d_in[5];
    const float* db1 = (const float*)d_in[6];
    const float* dWo = (const float*)d_in[7];
    const float* dbo = (const float*)d_in[8];
    const float* gW0 = (const float*)d_in[9];
    const float* gb0 = (const float*)d_in[10];
    const float* gW1 = (const float*)d_in[11];
    const float* gb1 = (const float*)d_in[12];
    const float* gWo = (const float*)d_in[13];
    const float* gbo = (const float*)d_in[14];
    const float* rW  = (const float*)d_in[15];
    const float* rb  = (const float*)d_in[16];
    float* out = (float*)d_out;

    sde_kernel<<<dim3(BATCH / RPB), dim3(NTH), 0, stream>>>(
        ts, dW, dW0, db0, dW1, db1, dWo, dbo,
        gW0, gb0, gW1, gb1, gWo, gbo, rW, rb, out);
}